// Round 14
// baseline (741.487 us; speedup 1.0000x reference)
//
#include <hip/hip_runtime.h>
#include <hip/hip_bf16.h>

#define B_SZ 8192
#define D_SZ 4096   // K
#define H_SZ 2048
#define N4H  8192   // 4*H = N (gate-interleaved n' space)
#define NT   (D_SZ / 64)   // 64 K-tiles of BK=64

typedef __attribute__((ext_vector_type(8)))  __bf16 bf16x8;
typedef __attribute__((ext_vector_type(4)))  float  f32x4;
typedef __attribute__((ext_vector_type(16))) float  f32x16;

#define GPTR(p) ((__attribute__((address_space(1))) void*)(p))
#define LPTR(p) ((__attribute__((address_space(3))) void*)(p))

// ---------------------------------------------------------------------------
// 1) prep: [blocks 0..2047]    combine = bf16(input + hidden)
//    [blocks 2048..34815]      WT[n'][k] = bf16(W_g[k][h]),
//               n' = (h>>5)*128 + g*32 + (h&31)   (gate-interleave, 32-granular)
// ---------------------------------------------------------------------------
__global__ void prep_k(const float* __restrict__ x, const float* __restrict__ h,
                       __hip_bfloat16* __restrict__ comb,
                       const float* __restrict__ Wf, const float* __restrict__ Wc,
                       const float* __restrict__ Wi, const float* __restrict__ Wo,
                       __hip_bfloat16* __restrict__ WT) {
    __shared__ float t[32][33];
    if (blockIdx.x < 2048) {
        const size_t n4 = (size_t)B_SZ * D_SZ / 4;
        const size_t stride = (size_t)2048 * 256;
        for (size_t i = (size_t)blockIdx.x * 256 + threadIdx.x; i < n4; i += stride) {
            f32x4 a = __builtin_nontemporal_load((const f32x4*)x + i);
            f32x4 b = __builtin_nontemporal_load((const f32x4*)h + i);
            short4 r;
            r.x = __builtin_bit_cast(short, __float2bfloat16(a.x + b.x));
            r.y = __builtin_bit_cast(short, __float2bfloat16(a.y + b.y));
            r.z = __builtin_bit_cast(short, __float2bfloat16(a.z + b.z));
            r.w = __builtin_bit_cast(short, __float2bfloat16(a.w + b.w));
            ((short4*)comb)[i] = r;
        }
    } else {
        const int b = blockIdx.x - 2048;      // 0..32767
        const int k0 = (b & 127) * 32;        // K block
        const int n0 = (b >> 7) * 32;         // old-layout n block (g*2048 + h)
        const float* W = (n0 < H_SZ) ? Wf : (n0 < 2 * H_SZ) ? Wc
                       : (n0 < 3 * H_SZ) ? Wi : Wo;
        const int g = n0 >> 11;
        const int nc = n0 & (H_SZ - 1);
        const int tx = threadIdx.x & 31, ty = threadIdx.x >> 5;
#pragma unroll
        for (int j = 0; j < 4; ++j)
            t[ty + j * 8][tx] = __builtin_nontemporal_load(
                W + (size_t)(k0 + ty + j * 8) * H_SZ + nc + tx);
        __syncthreads();
#pragma unroll
        for (int j = 0; j < 4; ++j) {
            const int h2 = nc + ty + j * 8;                       // h index
            const int np = ((h2 >> 5) << 7) + (g << 5) + (h2 & 31);
            WT[(size_t)np * D_SZ + k0 + tx] = __float2bfloat16(t[tx][ty + j * 8]);
        }
    }
}

// ---------------------------------------------------------------------------
// 2) GEMM + fused LSTM epilogue (v10: 32x32x16 MFMA on the r11 skeleton).
//    Block tile 128(M)x256(N), BK=64, 4 waves (2Mx2N), wave-tile 64x128 =
//    2(mt) x 4(j) tiles of 32x32. 32 MFMAs/tile/wave (vs 64 of 16x16x32);
//    same 24 ds_read_b128 and 12 stage-instr per tile.
//    LDS 80KB/block (2 blocks/CU = 160KB exactly):
//      A  [128 rows][128B] @ 0       regions A_mt = rows {mt*32+c*64}
//      B0 [256 rows][128B] @ 16384   (tile parity buffers)
//      B1 [256 rows][128B] @ 49152
//    Fragment layouts: A row=lane&31, k=(lane>>5)*8+i (16x16-verified pattern
//    K-doubled); B symmetric from BT rows; C/D col=lane&31,
//    row=(reg&3)+8*(reg>>2)+4*(lane>>5) [guide m74/m101-verified].
//    Schedule (1 barrier/phase; stages at top; WAR-after-barrier as r11):
//      ph1: stage Bj01(t+1)->OTH; read a0<-A0, b<-B(t)j01; MFMA mt0xj01; vmcnt(4)
//      ph2: stage A0(t+1);        read a1<-A1;             MFMA mt1xj01
//      ph3: stage Bj23(t+1)->OTH; read b<-B(t)j23;         MFMA mt0xj23
//      ph4: stage A1(t+1);                                 MFMA mt1xj23; vmcnt(6)
//    vmcnt audit (STAGE_Bp=4 loads, STAGE_A=2):
//      end-ph1 drains Bj23(t)+A1(t)   [ph2 reads A1(t), ph3 reads Bj23(t)]
//              leave Bj01(t+1)4 -> vmcnt(4)
//      end-ph4 drains ...A0(t+1)      [ph1(t+1) reads Bj01(t+1),A0(t+1)]
//              leave Bj23(t+1)4+A1(t+1)2 -> vmcnt(6)
//    Region WAR: A0 read ph1/staged ph2; A1 read ph2/staged ph4; B halves
//    read as cur one tile after staged into oth -> all >=1 barrier apart.
// ---------------------------------------------------------------------------

#define LDS_BB0 16384
#define LDS_BB1 49152

#define BAR()                                    \
    do {                                         \
        asm volatile("" ::: "memory");           \
        __builtin_amdgcn_s_barrier();            \
        asm volatile("" ::: "memory");           \
    } while (0)

// A region mt of K-tile kt (64 rows = 2 calls x 8-rows-per-call x 4 waves)
#define STAGE_A(mt, kt)                                                                \
    do {                                                                               \
        _Pragma("unroll") for (int c_ = 0; c_ < 2; ++c_) {                             \
            const int ro_ = c_ * 64 + (mt) * 32;                                       \
            __builtin_amdgcn_global_load_lds(                                          \
                GPTR(pA + (size_t)ro_ * D_SZ + (size_t)(kt) * 64),                     \
                LPTR(smem + (ro_ + wave * 8) * 128), 16, 0, 0);                        \
        }                                                                              \
    } while (0)

// B j-pair jp of K-tile kt -> buffer bb (rows {jp*64..+64} of each wc half)
#define STAGE_Bp(jp, kt, bb)                                                           \
    do {                                                                               \
        _Pragma("unroll") for (int c_ = 0; c_ < 4; ++c_) {                             \
            const int ro_ = (c_ >> 1) * 128 + (jp) * 64 + (c_ & 1) * 32;               \
            __builtin_amdgcn_global_load_lds(                                          \
                GPTR(pB + (size_t)ro_ * D_SZ + (size_t)(kt) * 64),                     \
                LPTR(smem + (bb) + (ro_ + wave * 8) * 128), 16, 0, 0);                 \
        }                                                                              \
    } while (0)

#define LDA(mt, AOFF)                                                                  \
    do {                                                                               \
        _Pragma("unroll") for (int k_ = 0; k_ < 4; ++k_)                               \
            a[mt][k_] = *(const bf16x8*)(smem + (AOFF) + swk[k_]);                     \
    } while (0)

#define LDB2(jp, BUFB)                                                                 \
    do {                                                                               \
        _Pragma("unroll") for (int jj_ = 0; jj_ < 2; ++jj_)                            \
        _Pragma("unroll") for (int k_ = 0; k_ < 4; ++k_)                               \
            b[jj_][k_] = *(const bf16x8*)(smem + (BUFB) + boff[(jp) * 2 + jj_]         \
                                          + swk[k_]);                                  \
    } while (0)

#define MFMA_P(mt, jp)                                                                 \
    do {                                                                               \
        _Pragma("unroll") for (int k_ = 0; k_ < 4; ++k_)                               \
        _Pragma("unroll") for (int jj_ = 0; jj_ < 2; ++jj_)                            \
            acc[mt][(jp) * 2 + jj_] = __builtin_amdgcn_mfma_f32_32x32x16_bf16(         \
                a[mt][k_], b[jj_][k_], acc[mt][(jp) * 2 + jj_], 0, 0, 0);              \
    } while (0)

#define TILE(KT, CURB, OTHB)                                                           \
    {                                                                                  \
        const int kt_ = (KT) & 63;                                                     \
        /* ph1 */                                                                      \
        STAGE_Bp(0, kt_, OTHB);                                                        \
        LDA(0, aoff0);                                                                 \
        LDB2(0, CURB);                                                                 \
        __builtin_amdgcn_s_setprio(1);                                                 \
        MFMA_P(0, 0);                                                                  \
        __builtin_amdgcn_s_setprio(0);                                                 \
        asm volatile("s_waitcnt vmcnt(4)" ::: "memory");                               \
        BAR();                                                                         \
        /* ph2 */                                                                      \
        STAGE_A(0, kt_);                                                               \
        LDA(1, aoff1);                                                                 \
        __builtin_amdgcn_s_setprio(1);                                                 \
        MFMA_P(1, 0);                                                                  \
        __builtin_amdgcn_s_setprio(0);                                                 \
        BAR();                                                                         \
        /* ph3 */                                                                      \
        STAGE_Bp(1, kt_, OTHB);                                                        \
        LDB2(1, CURB);                                                                 \
        __builtin_amdgcn_s_setprio(1);                                                 \
        MFMA_P(0, 1);                                                                  \
        __builtin_amdgcn_s_setprio(0);                                                 \
        BAR();                                                                         \
        /* ph4 */                                                                      \
        STAGE_A(1, kt_);                                                               \
        __builtin_amdgcn_s_setprio(1);                                                 \
        MFMA_P(1, 1);                                                                  \
        __builtin_amdgcn_s_setprio(0);                                                 \
        asm volatile("s_waitcnt vmcnt(6)" ::: "memory");                               \
        BAR();                                                                         \
    }

__device__ __forceinline__ float fsig(float x) { return 1.f / (1.f + __expf(-x)); }
__device__ __forceinline__ float ftanh(float x) {
    x = fminf(fmaxf(x, -15.f), 15.f);
    float e = __expf(2.f * x);
    return (e - 1.f) / (e + 1.f);
}

__global__ __launch_bounds__(256, 2) void gemm32_k(
    const __hip_bfloat16* __restrict__ A,   // comb [8192][4096]
    const __hip_bfloat16* __restrict__ BT,  // WT   [8192][4096] (gate-interleaved)
    const float* __restrict__ cell,         // [8192][2048]
    const float* __restrict__ bfb, const float* __restrict__ bcb,
    const float* __restrict__ bib, const float* __restrict__ bob,
    float* __restrict__ out)                // [out | hid | cst], each [8192][2048]
{
    extern __shared__ char smem[];

    const int tid  = threadIdx.x;
    const int wave = tid >> 6;
    const int lane = tid & 63;
    const int wr = wave >> 1;   // 0..1  (M halves of 64)
    const int wc = wave & 1;    // 0..1  (N halves of 128)
    const int l31 = lane & 31;
    const int l7  = lane & 7;   // == row&7 for all fragment rows
    const int khi = lane >> 5;  // 0..1

    // swizzled 16B-slot byte offsets per kstep (slot = k*2 + khi, ^ row&7)
    int swk[4];
#pragma unroll
    for (int k_ = 0; k_ < 4; ++k_) swk[k_] = ((k_ * 2 + khi) ^ l7) << 4;

    // fragment row byte bases
    const int aoff0 = (wr * 64 + 0 * 32 + l31) * 128;
    const int aoff1 = (wr * 64 + 1 * 32 + l31) * 128;
    int boff[4];
#pragma unroll
    for (int j_ = 0; j_ < 4; ++j_) boff[j_] = (wc * 128 + j_ * 32 + l31) * 128;

    // XCD-aware swizzle (bijective: 2048 % 8 == 0); ntile fastest.
    const int wg = (blockIdx.x & 7) * 256 + (blockIdx.x >> 3);
    const int ntile = wg & 31;          // 0..31 (N=256 tiles)
    const int m0 = (wg >> 5) * 128;     // 0..63 m-tiles
    const int n0 = ntile * 256;

    // staging sources (pre-swizzled global column; 8 rows per call per wave)
    const int r8   = tid >> 3;                           // 0..31
    const int gcol = ((tid & 7) ^ (r8 & 7)) << 3;
    const __hip_bfloat16* pA = A  + (size_t)(m0 + r8) * D_SZ + gcol;
    const __hip_bfloat16* pB = BT + (size_t)(n0 + r8) * D_SZ + gcol;

    f32x16 acc[2][4] = {};
    bf16x8 a[2][4], b[2][4];

    // prologue: stage tile0 in steady FIFO order; vmcnt(6) drains Bj01+A0.
    STAGE_Bp(0, 0, LDS_BB0);
    STAGE_A(0, 0);
    STAGE_Bp(1, 0, LDS_BB0);
    STAGE_A(1, 0);
    asm volatile("s_waitcnt vmcnt(6)" ::: "memory");
    BAR();

#pragma unroll 1
    for (int t = 0; t < NT; t += 2) {
        TILE(t + 1, LDS_BB0, LDS_BB1);   // even tile t (buf0), stage t+1 -> buf1
        TILE(t + 2, LDS_BB1, LDS_BB0);   // odd tile t+1 (buf1); t=63 stages kt=0 dummy
    }

    // ---- fused LSTM epilogue
    // C/D: col=lane&31, row=(reg&3)+8*(reg>>2)+4*(lane>>5)  [m74/m101]
    // n' = n0 + wc*128 + j*32 + col  ->  gate = j, h = (ntile*2+wc)*32 + col
    {
        const int rbase = khi * 4;
        const int hh = (ntile * 2 + wc) * 32 + l31;
        const float bf_ = bfb[hh], bc_ = bcb[hh], bi_ = bib[hh], bo_ = bob[hh];
        const size_t BH = (size_t)B_SZ * H_SZ;
        float* hidp = out + BH;
        float* cstp = out + 2 * BH;
#pragma unroll
        for (int mt = 0; mt < 2; ++mt) {
#pragma unroll
            for (int reg = 0; reg < 16; ++reg) {
                const int rr = (reg & 3) + 8 * (reg >> 2) + rbase;
                const size_t r = (size_t)(m0 + wr * 64 + mt * 32 + rr);
                const size_t idx = r * H_SZ + hh;
                const float gf = acc[mt][0][reg] + bf_;
                const float gc = acc[mt][1][reg] + bc_;
                const float gi = acc[mt][2][reg] + bi_;
                const float go = acc[mt][3][reg] + bo_;
                const float ft = fsig(gf);
                const float ct = ftanh(gc);
                const float it_ = fsig(fsig(gi));   // double sigmoid, faithful
                const float ot = fsig(go);
                const float cv = __builtin_nontemporal_load(cell + idx);
                const float cs = cv * ft + ct * it_;
                __builtin_nontemporal_store(ot, out + idx);
                __builtin_nontemporal_store(cs, cstp + idx);
                __builtin_nontemporal_store(ot * ftanh(cs), hidp + idx);
            }
        }
    }

    // drain dummy prefetch before endpgm — next block reuses this LDS
    asm volatile("s_waitcnt vmcnt(0)" ::: "memory");
}

// ---------------------------------------------------------------------------
extern "C" void kernel_launch(void* const* d_in, const int* in_sizes, int n_in,
                              void* d_out, int out_size, void* d_ws, size_t ws_size,
                              hipStream_t stream) {
    const float* input  = (const float*)d_in[0];
    const float* hidden = (const float*)d_in[1];
    const float* cell   = (const float*)d_in[2];
    const float* Wf     = (const float*)d_in[3];
    const float* bfb    = (const float*)d_in[4];
    const float* Wc     = (const float*)d_in[5];
    const float* bcb    = (const float*)d_in[6];
    const float* Wi     = (const float*)d_in[7];
    const float* bib    = (const float*)d_in[8];
    const float* Wo     = (const float*)d_in[9];
    const float* bob    = (const float*)d_in[10];
    float* out = (float*)d_out;

    char* ws = (char*)d_ws;
    __hip_bfloat16* comb = (__hip_bfloat16*)ws;                              // 64 MiB
    __hip_bfloat16* WT   = (__hip_bfloat16*)(ws + (size_t)B_SZ * D_SZ * 2);  // 64 MiB

    hipFuncSetAttribute(reinterpret_cast<const void*>(gemm32_k),
                        hipFuncAttributeMaxDynamicSharedMemorySize, 81920);

    prep_k<<<2048 + 32768, 256, 0, stream>>>(input, hidden, comb, Wf, Wc, Wi, Wo, WT);
    gemm32_k<<<2048, 256, 81920, stream>>>(comb, WT, cell, bfb, bcb, bib, bob, out);
}